// Round 21
// baseline (293.174 us; speedup 1.0000x reference)
//
#include <hip/hip_runtime.h>
#include <hip/hip_fp16.h>
#include <math.h>

#define BLK 256
#define CBSH 9           // 512 nodes per coarse bucket (196 buckets for n=100k)
#define CBN 512
#define NCBC 256
#define NB2 512

__device__ __forceinline__ float selu_f(float x) {
    const float kScale = 1.0507009873554805f;
    const float kAlpha = 1.6732632423543772f;
    return x > 0.0f ? kScale * x : kScale * kAlpha * expm1f(x);
}

__device__ __forceinline__ float2 h2f2(unsigned u) {
    __half2 h = *reinterpret_cast<__half2*>(&u);
    return __half22float2(h);
}
__device__ __forceinline__ void h4_set(float* a, uint2 v) {
    float2 f0 = h2f2(v.x), f1 = h2f2(v.y);
    a[0] = f0.x; a[1] = f0.y; a[2] = f1.x; a[3] = f1.y;
}
__device__ __forceinline__ void h4_add(float* a, uint2 v) {
    float2 f0 = h2f2(v.x), f1 = h2f2(v.y);
    a[0] += f0.x; a[1] += f0.y; a[2] += f1.x; a[3] += f1.y;
}
__device__ __forceinline__ uint4 f8_pack(const float* a) {
    __half2 h0 = __float22half2_rn(make_float2(a[0], a[1]));
    __half2 h1 = __float22half2_rn(make_float2(a[2], a[3]));
    __half2 h2 = __float22half2_rn(make_float2(a[4], a[5]));
    __half2 h3 = __float22half2_rn(make_float2(a[6], a[7]));
    uint4 u;
    u.x = *reinterpret_cast<unsigned*>(&h0);
    u.y = *reinterpret_cast<unsigned*>(&h1);
    u.z = *reinterpret_cast<unsigned*>(&h2);
    u.w = *reinterpret_cast<unsigned*>(&h3);
    return u;
}

// ---------------- CSR build (two-pass counting sort + fused build; verbatim) ----------------
__global__ void k_cnt(const int* __restrict__ dst, int* __restrict__ H, int e, int nbkt) {
    __shared__ int hist[NCBC];
    int tid = threadIdx.x;
    for (int b = tid; b < nbkt; b += BLK) hist[b] = 0;
    __syncthreads();
    int per = (e + NB2 - 1) / NB2;
    int lo = blockIdx.x * per;
    int hi = min(e, lo + per);
    for (int i = lo + tid; i < hi; i += BLK) atomicAdd(&hist[dst[i] >> CBSH], 1);
    __syncthreads();
    for (int b = tid; b < nbkt; b += BLK) H[blockIdx.x * nbkt + b] = hist[b];
}

__global__ void k_bsum(const int* __restrict__ H, int* __restrict__ bstart, int nbkt, int e) {
    __shared__ int tot[NCBC];
    int tid = threadIdx.x;
    for (int b = tid; b < nbkt; b += BLK) {
        int s = 0;
        for (int i = 0; i < NB2; ++i) s += H[i * nbkt + b];
        tot[b] = s;
    }
    __syncthreads();
    if (tid == 0) {
        int acc = 0;
        for (int b = 0; b < nbkt; ++b) {
            bstart[b] = acc;
            acc += tot[b];
        }
        bstart[nbkt] = acc;  // == e
    }
}

__global__ void k_off(int* __restrict__ H, const int* __restrict__ bstart, int nbkt) {
    __shared__ int lds[BLK];
    int b = blockIdx.x, tid = threadIdx.x;
    int v0 = H[(2 * tid) * nbkt + b];
    int v1 = H[(2 * tid + 1) * nbkt + b];
    int pair = v0 + v1;
    lds[tid] = pair;
    __syncthreads();
    int val = pair;
    for (int off = 1; off < BLK; off <<= 1) {
        int t2 = (tid >= off) ? lds[tid - off] : 0;
        __syncthreads();
        val += t2;
        lds[tid] = val;
        __syncthreads();
    }
    int excl = val - pair + bstart[b];
    H[(2 * tid) * nbkt + b] = excl;
    H[(2 * tid + 1) * nbkt + b] = excl + v0;
}

__global__ void k_scatter2(const int* __restrict__ src, const int* __restrict__ dst,
                           const int* __restrict__ H, unsigned* __restrict__ slab,
                           int e, int nbkt) {
    __shared__ int cur[NCBC];
    int tid = threadIdx.x;
    for (int b = tid; b < nbkt; b += BLK) cur[b] = H[blockIdx.x * nbkt + b];
    __syncthreads();
    int per = (e + NB2 - 1) / NB2;
    int lo = blockIdx.x * per;
    int hi = min(e, lo + per);
    for (int i = lo + tid; i < hi; i += BLK) {
        int s = src[i], d = dst[i];
        int b = d >> CBSH;
        int pos = atomicAdd(&cur[b], 1);
        slab[pos] = ((unsigned)s << CBSH) | (unsigned)(d & (CBN - 1));
    }
}

__global__ void k_build(const int* __restrict__ bstart, const unsigned* __restrict__ slab,
                        int* __restrict__ rowptr, float* __restrict__ dinv,
                        int* __restrict__ csr, int n, int e) {
    __shared__ int hist[CBN];
    __shared__ int stmp[BLK];
    int b = blockIdx.x, tid = threadIdx.x;
    hist[2 * tid] = 0;
    hist[2 * tid + 1] = 0;
    __syncthreads();
    int lo = bstart[b], hi = bstart[b + 1];
    for (int i = lo + tid; i < hi; i += BLK) atomicAdd(&hist[slab[i] & (CBN - 1)], 1);
    __syncthreads();
    int h0 = hist[2 * tid], h1 = hist[2 * tid + 1];
    int pair = h0 + h1;
    stmp[tid] = pair;
    __syncthreads();
    int val = pair;
    for (int off = 1; off < BLK; off <<= 1) {
        int t2 = (tid >= off) ? stmp[tid - off] : 0;
        __syncthreads();
        val += t2;
        stmp[tid] = val;
        __syncthreads();
    }
    int e0 = lo + val - pair;
    int e1 = e0 + h0;
    hist[2 * tid] = e0;
    hist[2 * tid + 1] = e1;
    int node0 = b << CBSH;
    int nA = node0 + 2 * tid, nB = nA + 1;
    if (nA < n) { rowptr[nA] = e0; dinv[nA] = rsqrtf((float)(h0 + 1)); }
    if (nB < n) { rowptr[nB] = e1; dinv[nB] = rsqrtf((float)(h1 + 1)); }
    if (b == 0 && tid == 0) rowptr[n] = e;
    __syncthreads();
    for (int i = lo + tid; i < hi; i += BLK) {
        unsigned p = slab[i];
        int pos = atomicAdd(&hist[p & (CBN - 1)], 1);
        csr[pos] = (int)(p >> CBSH);
    }
}

// ---------------- layer compute ----------------
// gemm1: hs1 = fp16(dinv * (x @ W1)), stride 16h.
__global__ void k_gemm1(const float* __restrict__ xin, const float* __restrict__ W,
                        const float* __restrict__ dinv, __half* __restrict__ hs, int n) {
    int i = blockIdx.x * BLK + threadIdx.x;
    if (i >= n) return;
    const float* xr = xin + (size_t)i * 128;
    float accf[16];
#pragma unroll
    for (int f = 0; f < 16; ++f) accf[f] = 0.0f;
#pragma unroll
    for (int k4 = 0; k4 < 32; ++k4) {
        float4 xv = *reinterpret_cast<const float4*>(xr + k4 * 4);
        float xs4[4] = {xv.x, xv.y, xv.z, xv.w};
#pragma unroll
        for (int j = 0; j < 4; ++j) {
            const int k = k4 * 4 + j;
#pragma unroll
            for (int f = 0; f < 15; ++f) accf[f] = fmaf(xs4[j], W[k * 15 + f], accf[f]);
        }
    }
    float di = dinv[i];
#pragma unroll
    for (int f = 0; f < 15; ++f) accf[f] *= di;
    accf[15] = 0.0f;
    __half2* ro2 = reinterpret_cast<__half2*>(hs + (size_t)i * 16);
#pragma unroll
    for (int f2 = 0; f2 < 8; ++f2)
        ro2[f2] = __float22half2_rn(make_float2(accf[2 * f2], accf[2 * f2 + 1]));
}

// Fused agg_l + gemm_{l+1}: uint2 chunk grain (4 halves/lane) -> CHI lanes/node.
// Gather (r20 pipelined loop) -> input epilogue -> shfl K-row exchange ->
// lane fl < CHO computes output chunk fl and writes fp16 hs_out.
template <int CHI, int NPN, int SIN, int K, int FN, int CHO, int SON>
__global__ void k_aggemm(const int* __restrict__ rowptr, const int* __restrict__ csr,
                         const __half* __restrict__ hsin, const float* __restrict__ bprev,
                         const float* __restrict__ dinv, const float* __restrict__ W,
                         __half* __restrict__ hsout, int n) {
    int lane = threadIdx.x & 63;
    int g = lane / CHI;
    int fl = lane - g * CHI;
    int wid = (blockIdx.x * BLK + threadIdx.x) >> 6;
    int d = wid * NPN + g;
    bool active = (g < NPN) && (d < n);
    float xv4[4];
#pragma unroll
    for (int j = 0; j < 4; ++j) xv4[j] = 0.0f;
    float di = 0.0f;
    if (active) {
        di = dinv[d];
        int beg = rowptr[d], end = rowptr[d + 1];
        auto rowp = [&](int r) {
            return reinterpret_cast<const uint2*>(hsin + (size_t)r * SIN) + fl;
        };
        float s0[4], s1[4] = {0}, s2[4] = {0}, s3[4] = {0};
        h4_set(s0, *rowp(d));  // self
        int p = beg;
        int e0, e1, e2, e3, e4, e5, e6, e7;
        bool have = (p + 8 <= end);
        if (have) {
            e0 = __builtin_nontemporal_load(csr + p);
            e1 = __builtin_nontemporal_load(csr + p + 1);
            e2 = __builtin_nontemporal_load(csr + p + 2);
            e3 = __builtin_nontemporal_load(csr + p + 3);
            e4 = __builtin_nontemporal_load(csr + p + 4);
            e5 = __builtin_nontemporal_load(csr + p + 5);
            e6 = __builtin_nontemporal_load(csr + p + 6);
            e7 = __builtin_nontemporal_load(csr + p + 7);
            p += 8;
        }
        while (have) {
            uint2 v0 = *rowp(e0), v1 = *rowp(e1), v2 = *rowp(e2), v3 = *rowp(e3);
            uint2 v4 = *rowp(e4), v5 = *rowp(e5), v6 = *rowp(e6), v7 = *rowp(e7);
            bool nxt = (p + 8 <= end);
            int f0 = 0, f1 = 0, f2 = 0, f3 = 0, f4 = 0, f5 = 0, f6 = 0, f7 = 0;
            if (nxt) {  // prefetch next batch's indices
                f0 = __builtin_nontemporal_load(csr + p);
                f1 = __builtin_nontemporal_load(csr + p + 1);
                f2 = __builtin_nontemporal_load(csr + p + 2);
                f3 = __builtin_nontemporal_load(csr + p + 3);
                f4 = __builtin_nontemporal_load(csr + p + 4);
                f5 = __builtin_nontemporal_load(csr + p + 5);
                f6 = __builtin_nontemporal_load(csr + p + 6);
                f7 = __builtin_nontemporal_load(csr + p + 7);
                p += 8;
            }
            h4_add(s0, v0); h4_add(s1, v1); h4_add(s2, v2); h4_add(s3, v3);
            h4_add(s0, v4); h4_add(s1, v5); h4_add(s2, v6); h4_add(s3, v7);
            e0 = f0; e1 = f1; e2 = f2; e3 = f3; e4 = f4; e5 = f5; e6 = f6; e7 = f7;
            have = nxt;
        }
        for (; p + 4 <= end; p += 4) {
            int a0 = __builtin_nontemporal_load(csr + p);
            int a1 = __builtin_nontemporal_load(csr + p + 1);
            int a2 = __builtin_nontemporal_load(csr + p + 2);
            int a3 = __builtin_nontemporal_load(csr + p + 3);
            uint2 v0 = *rowp(a0), v1 = *rowp(a1), v2 = *rowp(a2), v3 = *rowp(a3);
            h4_add(s0, v0); h4_add(s1, v1); h4_add(s2, v2); h4_add(s3, v3);
        }
        for (; p < end; ++p) h4_add(s0, *rowp(__builtin_nontemporal_load(csr + p)));
#pragma unroll
        for (int j = 0; j < 4; ++j) {
            int k = fl * 4 + j;
            if (k < K) {
                float s = (s0[j] + s1[j]) + (s2[j] + s3[j]);
                xv4[j] = selu_f(di * s + bprev[k]);  // input epilogue
            }
        }
    }
    // Wave-register exchange: xk[k] = group g's K-row (chunk k>>2 at lane base+(k>>2)).
    int base = lane - fl;  // = g * CHI
    float xk[K];
#pragma unroll
    for (int k = 0; k < K; ++k)
        xk[k] = __shfl(xv4[k & 3], (base + (k >> 2)) & 63, 64);
    if (active && fl < CHO) {
        int c = fl;
        float acc[8];
#pragma unroll
        for (int j = 0; j < 8; ++j) acc[j] = 0.0f;
#pragma unroll
        for (int k = 0; k < K; ++k) {
#pragma unroll
            for (int j = 0; j < 8; ++j) {
                int col = c * 8 + j;
                if (col < FN) acc[j] = fmaf(xk[k], W[k * FN + col], acc[j]);
            }
        }
        float gg[8];
#pragma unroll
        for (int j = 0; j < 8; ++j) {
            int col = c * 8 + j;
            gg[j] = (col < FN) ? di * acc[j] : 0.0f;
        }
        *reinterpret_cast<uint4*>(hsout + (size_t)d * SON + c * 8) = f8_pack(gg);
    }
}

// Final gather, uint2 grain: ACT=9 lanes/node (36 cols = 9 float4 outputs), fused epilogue.
template <int F, int S, int ACT, int NPN>
__global__ void k_aggL(const int* __restrict__ rowptr, const int* __restrict__ csr,
                       const __half* __restrict__ hs, float* __restrict__ out,
                       const float* __restrict__ dinv, const float* __restrict__ bias,
                       int n) {
    int lane = threadIdx.x & 63;
    int g = lane / ACT;
    int fl = lane - g * ACT;
    int wid = (blockIdx.x * BLK + threadIdx.x) >> 6;
    int d = wid * NPN + g;
    if (g >= NPN || d >= n) return;
    int beg = rowptr[d], end = rowptr[d + 1];
    auto rowp = [&](int r) {
        return reinterpret_cast<const uint2*>(hs + (size_t)r * S) + fl;
    };
    float s0[4], s1[4] = {0}, s2[4] = {0}, s3[4] = {0};
    h4_set(s0, *rowp(d));  // self
    int p = beg;
    int e0, e1, e2, e3, e4, e5, e6, e7;
    bool have = (p + 8 <= end);
    if (have) {
        e0 = __builtin_nontemporal_load(csr + p);
        e1 = __builtin_nontemporal_load(csr + p + 1);
        e2 = __builtin_nontemporal_load(csr + p + 2);
        e3 = __builtin_nontemporal_load(csr + p + 3);
        e4 = __builtin_nontemporal_load(csr + p + 4);
        e5 = __builtin_nontemporal_load(csr + p + 5);
        e6 = __builtin_nontemporal_load(csr + p + 6);
        e7 = __builtin_nontemporal_load(csr + p + 7);
        p += 8;
    }
    while (have) {
        uint2 v0 = *rowp(e0), v1 = *rowp(e1), v2 = *rowp(e2), v3 = *rowp(e3);
        uint2 v4 = *rowp(e4), v5 = *rowp(e5), v6 = *rowp(e6), v7 = *rowp(e7);
        bool nxt = (p + 8 <= end);
        int f0 = 0, f1 = 0, f2 = 0, f3 = 0, f4 = 0, f5 = 0, f6 = 0, f7 = 0;
        if (nxt) {
            f0 = __builtin_nontemporal_load(csr + p);
            f1 = __builtin_nontemporal_load(csr + p + 1);
            f2 = __builtin_nontemporal_load(csr + p + 2);
            f3 = __builtin_nontemporal_load(csr + p + 3);
            f4 = __builtin_nontemporal_load(csr + p + 4);
            f5 = __builtin_nontemporal_load(csr + p + 5);
            f6 = __builtin_nontemporal_load(csr + p + 6);
            f7 = __builtin_nontemporal_load(csr + p + 7);
            p += 8;
        }
        h4_add(s0, v0); h4_add(s1, v1); h4_add(s2, v2); h4_add(s3, v3);
        h4_add(s0, v4); h4_add(s1, v5); h4_add(s2, v6); h4_add(s3, v7);
        e0 = f0; e1 = f1; e2 = f2; e3 = f3; e4 = f4; e5 = f5; e6 = f6; e7 = f7;
        have = nxt;
    }
    for (; p + 4 <= end; p += 4) {
        int a0 = __builtin_nontemporal_load(csr + p);
        int a1 = __builtin_nontemporal_load(csr + p + 1);
        int a2 = __builtin_nontemporal_load(csr + p + 2);
        int a3 = __builtin_nontemporal_load(csr + p + 3);
        uint2 v0 = *rowp(a0), v1 = *rowp(a1), v2 = *rowp(a2), v3 = *rowp(a3);
        h4_add(s0, v0); h4_add(s1, v1); h4_add(s2, v2); h4_add(s3, v3);
    }
    for (; p < end; ++p) h4_add(s0, *rowp(__builtin_nontemporal_load(csr + p)));
    float dv = dinv[d];
    float r[4];
#pragma unroll
    for (int j = 0; j < 4; ++j) {
        int col = fl * 4 + j;
        float s = (s0[j] + s1[j]) + (s2[j] + s3[j]);
        r[j] = (col < F) ? selu_f(dv * s + bias[col]) : 0.0f;
    }
    *reinterpret_cast<float4*>(out + (size_t)d * F + fl * 4) =
        make_float4(r[0], r[1], r[2], r[3]);
}

extern "C" void kernel_launch(void* const* d_in, const int* in_sizes, int n_in,
                              void* d_out, int out_size, void* d_ws, size_t ws_size,
                              hipStream_t stream) {
    const float* x = (const float*)d_in[0];
    const int* ei = (const int*)d_in[1];  // int32 on device
    const float* W1 = (const float*)d_in[2];
    const float* b1 = (const float*)d_in[3];
    const float* W2 = (const float*)d_in[4];
    const float* b2 = (const float*)d_in[5];
    const float* W3 = (const float*)d_in[6];
    const float* b3 = (const float*)d_in[7];
    const float* W4 = (const float*)d_in[8];
    const float* b4 = (const float*)d_in[9];

    int n = in_sizes[0] / 128;
    int e = in_sizes[1] / 2;
    const int* s32 = ei;
    const int* d32 = ei + e;
    int nbkt = (n + CBN - 1) >> CBSH;  // 196

    char* w = (char*)d_ws;
    auto alloc = [&](size_t bytes) {
        char* p = w;
        w += (bytes + 255) & ~(size_t)255;
        return p;
    };
    int* rowptr = (int*)alloc(((size_t)n + 1) * 4);
    float* dinv = (float*)alloc((size_t)n * 4);
    int* csr = (int*)alloc((size_t)e * 4);
    int* H = (int*)alloc((size_t)NB2 * nbkt * 4);
    int* bstart = (int*)alloc(((size_t)nbkt + 1) * 4);
    __half* bufA = (__half*)alloc((size_t)n * 40 * 2);  // hs1/hs3; aliases slab
    __half* bufC = (__half*)alloc((size_t)n * 40 * 2);  // hs2/hs4
    unsigned* slab = (unsigned*)bufA;   // e*4 = 6.4MB <= 8MB

    int nb = (n + BLK - 1) / BLK;

    // CSR build: counting sort + fused build
    k_cnt<<<NB2, BLK, 0, stream>>>(d32, H, e, nbkt);
    k_bsum<<<1, BLK, 0, stream>>>(H, bstart, nbkt, e);
    k_off<<<nbkt, BLK, 0, stream>>>(H, bstart, nbkt);
    k_scatter2<<<NB2, BLK, 0, stream>>>(s32, d32, H, slab, e, nbkt);
    k_build<<<nbkt, BLK, 0, stream>>>(bstart, slab, rowptr, dinv, csr, n, e);

    // grids: nodes/block = 4 waves * NPN (uint2 grain lane teams)
    int ab1 = (n + 63) / 64;   // CHI=4, NPN=16
    int ab2 = (n + 47) / 48;   // CHI=5, NPN=12
    int ab3 = (n + 35) / 36;   // CHI=7, NPN=9
    int ab4 = (n + 27) / 28;   // ACT=9, NPN=7

    // layer 1 gemm: x @ W1 -> hs1 (bufA, stride 16h)
    k_gemm1<<<nb, BLK, 0, stream>>>(x, W1, dinv, bufA, n);

    // fused agg1+gemm2: gather hs1 (4 uint2 chunks) -> selu -> @W2 -> hs2 (bufC, 32h)
    k_aggemm<4, 16, 16, 15, 20, 3, 32><<<ab1, BLK, 0, stream>>>(
        rowptr, csr, bufA, b1, dinv, W2, bufC, n);

    // fused agg2+gemm3: gather hs2 (5 uint2 chunks) -> @W3 -> hs3 (bufA, 32h)
    k_aggemm<5, 12, 32, 20, 27, 4, 32><<<ab2, BLK, 0, stream>>>(
        rowptr, csr, bufC, b2, dinv, W3, bufA, n);

    // fused agg3+gemm4: gather hs3 (7 uint2 chunks) -> @W4 -> hs4 (bufC, 40h)
    k_aggemm<7, 9, 32, 27, 36, 5, 40><<<ab3, BLK, 0, stream>>>(
        rowptr, csr, bufA, b3, dinv, W4, bufC, n);

    // final agg: gather hs4 (9 uint2 chunks), fused selu/bias epilogue -> d_out
    k_aggL<36, 40, 9, 7><<<ab4, BLK, 0, stream>>>(rowptr, csr, bufC, (float*)d_out, dinv, b4, n);
}

// Round 22
// 246.999 us; speedup vs baseline: 1.1869x; 1.1869x over previous
//
#include <hip/hip_runtime.h>
#include <hip/hip_fp16.h>
#include <math.h>

#define BLK 256
#define CBSH 9           // 512 nodes per coarse bucket (196 buckets for n=100k)
#define CBN 512
#define NCBC 256
#define NB2 512

__device__ __forceinline__ float selu_f(float x) {
    const float kScale = 1.0507009873554805f;
    const float kAlpha = 1.6732632423543772f;
    return x > 0.0f ? kScale * x : kScale * kAlpha * expm1f(x);
}

__device__ __forceinline__ float2 h2f2(unsigned u) {
    __half2 h = *reinterpret_cast<__half2*>(&u);
    return __half22float2(h);
}
__device__ __forceinline__ void h8_set(float* a, uint4 v) {
    float2 f0 = h2f2(v.x), f1 = h2f2(v.y), f2 = h2f2(v.z), f3 = h2f2(v.w);
    a[0] = f0.x; a[1] = f0.y; a[2] = f1.x; a[3] = f1.y;
    a[4] = f2.x; a[5] = f2.y; a[6] = f3.x; a[7] = f3.y;
}
__device__ __forceinline__ void h8_add(float* a, uint4 v) {
    float2 f0 = h2f2(v.x), f1 = h2f2(v.y), f2 = h2f2(v.z), f3 = h2f2(v.w);
    a[0] += f0.x; a[1] += f0.y; a[2] += f1.x; a[3] += f1.y;
    a[4] += f2.x; a[5] += f2.y; a[6] += f3.x; a[7] += f3.y;
}
__device__ __forceinline__ uint4 f8_pack(const float* a) {
    __half2 h0 = __float22half2_rn(make_float2(a[0], a[1]));
    __half2 h1 = __float22half2_rn(make_float2(a[2], a[3]));
    __half2 h2 = __float22half2_rn(make_float2(a[4], a[5]));
    __half2 h3 = __float22half2_rn(make_float2(a[6], a[7]));
    uint4 u;
    u.x = *reinterpret_cast<unsigned*>(&h0);
    u.y = *reinterpret_cast<unsigned*>(&h1);
    u.z = *reinterpret_cast<unsigned*>(&h2);
    u.w = *reinterpret_cast<unsigned*>(&h3);
    return u;
}

// ---------------- CSR build (two-pass counting sort + fused build; verbatim) ----------------
__global__ void k_cnt(const int* __restrict__ dst, int* __restrict__ H, int e, int nbkt) {
    __shared__ int hist[NCBC];
    int tid = threadIdx.x;
    for (int b = tid; b < nbkt; b += BLK) hist[b] = 0;
    __syncthreads();
    int per = (e + NB2 - 1) / NB2;
    int lo = blockIdx.x * per;
    int hi = min(e, lo + per);
    for (int i = lo + tid; i < hi; i += BLK) atomicAdd(&hist[dst[i] >> CBSH], 1);
    __syncthreads();
    for (int b = tid; b < nbkt; b += BLK) H[blockIdx.x * nbkt + b] = hist[b];
}

__global__ void k_bsum(const int* __restrict__ H, int* __restrict__ bstart, int nbkt, int e) {
    __shared__ int tot[NCBC];
    int tid = threadIdx.x;
    for (int b = tid; b < nbkt; b += BLK) {
        int s = 0;
        for (int i = 0; i < NB2; ++i) s += H[i * nbkt + b];
        tot[b] = s;
    }
    __syncthreads();
    if (tid == 0) {
        int acc = 0;
        for (int b = 0; b < nbkt; ++b) {
            bstart[b] = acc;
            acc += tot[b];
        }
        bstart[nbkt] = acc;  // == e
    }
}

__global__ void k_off(int* __restrict__ H, const int* __restrict__ bstart, int nbkt) {
    __shared__ int lds[BLK];
    int b = blockIdx.x, tid = threadIdx.x;
    int v0 = H[(2 * tid) * nbkt + b];
    int v1 = H[(2 * tid + 1) * nbkt + b];
    int pair = v0 + v1;
    lds[tid] = pair;
    __syncthreads();
    int val = pair;
    for (int off = 1; off < BLK; off <<= 1) {
        int t2 = (tid >= off) ? lds[tid - off] : 0;
        __syncthreads();
        val += t2;
        lds[tid] = val;
        __syncthreads();
    }
    int excl = val - pair + bstart[b];
    H[(2 * tid) * nbkt + b] = excl;
    H[(2 * tid + 1) * nbkt + b] = excl + v0;
}

__global__ void k_scatter2(const int* __restrict__ src, const int* __restrict__ dst,
                           const int* __restrict__ H, unsigned* __restrict__ slab,
                           int e, int nbkt) {
    __shared__ int cur[NCBC];
    int tid = threadIdx.x;
    for (int b = tid; b < nbkt; b += BLK) cur[b] = H[blockIdx.x * nbkt + b];
    __syncthreads();
    int per = (e + NB2 - 1) / NB2;
    int lo = blockIdx.x * per;
    int hi = min(e, lo + per);
    for (int i = lo + tid; i < hi; i += BLK) {
        int s = src[i], d = dst[i];
        int b = d >> CBSH;
        int pos = atomicAdd(&cur[b], 1);
        slab[pos] = ((unsigned)s << CBSH) | (unsigned)(d & (CBN - 1));
    }
}

__global__ void k_build(const int* __restrict__ bstart, const unsigned* __restrict__ slab,
                        int* __restrict__ rowptr, float* __restrict__ dinv,
                        int* __restrict__ csr, int n, int e) {
    __shared__ int hist[CBN];
    __shared__ int stmp[BLK];
    int b = blockIdx.x, tid = threadIdx.x;
    hist[2 * tid] = 0;
    hist[2 * tid + 1] = 0;
    __syncthreads();
    int lo = bstart[b], hi = bstart[b + 1];
    for (int i = lo + tid; i < hi; i += BLK) atomicAdd(&hist[slab[i] & (CBN - 1)], 1);
    __syncthreads();
    int h0 = hist[2 * tid], h1 = hist[2 * tid + 1];
    int pair = h0 + h1;
    stmp[tid] = pair;
    __syncthreads();
    int val = pair;
    for (int off = 1; off < BLK; off <<= 1) {
        int t2 = (tid >= off) ? stmp[tid - off] : 0;
        __syncthreads();
        val += t2;
        stmp[tid] = val;
        __syncthreads();
    }
    int e0 = lo + val - pair;
    int e1 = e0 + h0;
    hist[2 * tid] = e0;
    hist[2 * tid + 1] = e1;
    int node0 = b << CBSH;
    int nA = node0 + 2 * tid, nB = nA + 1;
    if (nA < n) { rowptr[nA] = e0; dinv[nA] = rsqrtf((float)(h0 + 1)); }
    if (nB < n) { rowptr[nB] = e1; dinv[nB] = rsqrtf((float)(h1 + 1)); }
    if (b == 0 && tid == 0) rowptr[n] = e;
    __syncthreads();
    for (int i = lo + tid; i < hi; i += BLK) {
        unsigned p = slab[i];
        int pos = atomicAdd(&hist[p & (CBN - 1)], 1);
        csr[pos] = (int)(p >> CBSH);
    }
}

// ---------------- layer compute ----------------
// gemm1: hs1 = fp16(dinv * (x @ W1)), stride 16h.
__global__ void k_gemm1(const float* __restrict__ xin, const float* __restrict__ W,
                        const float* __restrict__ dinv, __half* __restrict__ hs, int n) {
    int i = blockIdx.x * BLK + threadIdx.x;
    if (i >= n) return;
    const float* xr = xin + (size_t)i * 128;
    float accf[16];
#pragma unroll
    for (int f = 0; f < 16; ++f) accf[f] = 0.0f;
#pragma unroll
    for (int k4 = 0; k4 < 32; ++k4) {
        float4 xv = *reinterpret_cast<const float4*>(xr + k4 * 4);
        float xs4[4] = {xv.x, xv.y, xv.z, xv.w};
#pragma unroll
        for (int j = 0; j < 4; ++j) {
            const int k = k4 * 4 + j;
#pragma unroll
            for (int f = 0; f < 15; ++f) accf[f] = fmaf(xs4[j], W[k * 15 + f], accf[f]);
        }
    }
    float di = dinv[i];
#pragma unroll
    for (int f = 0; f < 15; ++f) accf[f] *= di;
    accf[15] = 0.0f;
    __half2* ro2 = reinterpret_cast<__half2*>(hs + (size_t)i * 16);
#pragma unroll
    for (int f2 = 0; f2 < 8; ++f2)
        ro2[f2] = __float22half2_rn(make_float2(accf[2 * f2], accf[2 * f2 + 1]));
}

// Fused agg_l + gemm_{l+1} (round-18 structure; gather loop software-pipelined:
// batch i+1's csr indices load while batch i's row gathers are in flight).
template <int CHI, int NPN, int SIN, int K, int FN, int CHO, int SON>
__global__ void k_aggemm(const int* __restrict__ rowptr, const int* __restrict__ csr,
                         const __half* __restrict__ hsin, const float* __restrict__ bprev,
                         const float* __restrict__ dinv, const float* __restrict__ W,
                         __half* __restrict__ hsout, int n) {
    int lane = threadIdx.x & 63;
    int g = lane / CHI;
    int fl = lane - g * CHI;
    int wid = (blockIdx.x * BLK + threadIdx.x) >> 6;
    int d = wid * NPN + g;
    bool active = (g < NPN) && (d < n);
    float xv8[8];
#pragma unroll
    for (int j = 0; j < 8; ++j) xv8[j] = 0.0f;
    float di = 0.0f;
    if (active) {
        di = dinv[d];
        int beg = rowptr[d], end = rowptr[d + 1];
        auto rowp = [&](int r) {
            return reinterpret_cast<const uint4*>(hsin + (size_t)r * SIN) + fl;
        };
        float s0[8], s1[8] = {0}, s2[8] = {0}, s3[8] = {0};
        h8_set(s0, *rowp(d));  // self
        int p = beg;
        int e0, e1, e2, e3, e4, e5, e6, e7;
        bool have = (p + 8 <= end);
        if (have) {
            e0 = __builtin_nontemporal_load(csr + p);
            e1 = __builtin_nontemporal_load(csr + p + 1);
            e2 = __builtin_nontemporal_load(csr + p + 2);
            e3 = __builtin_nontemporal_load(csr + p + 3);
            e4 = __builtin_nontemporal_load(csr + p + 4);
            e5 = __builtin_nontemporal_load(csr + p + 5);
            e6 = __builtin_nontemporal_load(csr + p + 6);
            e7 = __builtin_nontemporal_load(csr + p + 7);
            p += 8;
        }
        while (have) {
            uint4 v0 = *rowp(e0), v1 = *rowp(e1), v2 = *rowp(e2), v3 = *rowp(e3);
            uint4 v4 = *rowp(e4), v5 = *rowp(e5), v6 = *rowp(e6), v7 = *rowp(e7);
            bool nxt = (p + 8 <= end);
            int f0 = 0, f1 = 0, f2 = 0, f3 = 0, f4 = 0, f5 = 0, f6 = 0, f7 = 0;
            if (nxt) {  // prefetch next batch's indices; overlaps the row gathers above
                f0 = __builtin_nontemporal_load(csr + p);
                f1 = __builtin_nontemporal_load(csr + p + 1);
                f2 = __builtin_nontemporal_load(csr + p + 2);
                f3 = __builtin_nontemporal_load(csr + p + 3);
                f4 = __builtin_nontemporal_load(csr + p + 4);
                f5 = __builtin_nontemporal_load(csr + p + 5);
                f6 = __builtin_nontemporal_load(csr + p + 6);
                f7 = __builtin_nontemporal_load(csr + p + 7);
                p += 8;
            }
            h8_add(s0, v0); h8_add(s1, v1); h8_add(s2, v2); h8_add(s3, v3);
            h8_add(s0, v4); h8_add(s1, v5); h8_add(s2, v6); h8_add(s3, v7);
            e0 = f0; e1 = f1; e2 = f2; e3 = f3; e4 = f4; e5 = f5; e6 = f6; e7 = f7;
            have = nxt;
        }
        for (; p + 4 <= end; p += 4) {
            int a0 = __builtin_nontemporal_load(csr + p);
            int a1 = __builtin_nontemporal_load(csr + p + 1);
            int a2 = __builtin_nontemporal_load(csr + p + 2);
            int a3 = __builtin_nontemporal_load(csr + p + 3);
            uint4 v0 = *rowp(a0), v1 = *rowp(a1), v2 = *rowp(a2), v3 = *rowp(a3);
            h8_add(s0, v0); h8_add(s1, v1); h8_add(s2, v2); h8_add(s3, v3);
        }
        for (; p < end; ++p) h8_add(s0, *rowp(__builtin_nontemporal_load(csr + p)));
#pragma unroll
        for (int j = 0; j < 8; ++j) {
            int k = fl * 8 + j;
            if (k < K) {
                float s = (s0[j] + s1[j]) + (s2[j] + s3[j]);
                xv8[j] = selu_f(di * s + bprev[k]);  // input epilogue (as old gemm)
            }
        }
    }
    // Wave-register exchange: all lanes converged; xk[k] = group g's K-row.
    int base = lane - fl;  // = g * CHI
    float xk[K];
#pragma unroll
    for (int k = 0; k < K; ++k)
        xk[k] = __shfl(xv8[k & 7], (base + (k >> 3)) & 63, 64);
    if (active) {
#pragma unroll
        for (int m = 0; m < (CHO + CHI - 1) / CHI; ++m) {
            int c = fl + m * CHI;
            if (c < CHO) {
                float acc[8];
#pragma unroll
                for (int j = 0; j < 8; ++j) acc[j] = 0.0f;
#pragma unroll
                for (int k = 0; k < K; ++k) {
#pragma unroll
                    for (int j = 0; j < 8; ++j) {
                        int col = c * 8 + j;
                        if (col < FN) acc[j] = fmaf(xk[k], W[k * FN + col], acc[j]);
                    }
                }
                float gg[8];
#pragma unroll
                for (int j = 0; j < 8; ++j) {
                    int col = c * 8 + j;
                    gg[j] = (col < FN) ? di * acc[j] : 0.0f;
                }
                *reinterpret_cast<uint4*>(hsout + (size_t)d * SON + c * 8) = f8_pack(gg);
            }
        }
    }
}

// Final CSR gather (round-18 layout; same pipelined gather loop; fused final epilogue).
template <int F, int S, int ACT, int NPN>
__global__ void k_aggL(const int* __restrict__ rowptr, const int* __restrict__ csr,
                       const __half* __restrict__ hs, float* __restrict__ out,
                       const float* __restrict__ dinv, const float* __restrict__ bias,
                       int n) {
    int lane = threadIdx.x & 63;
    int g = lane / ACT;
    int fl = lane - g * ACT;
    int wid = (blockIdx.x * BLK + threadIdx.x) >> 6;
    int d = wid * NPN + g;
    if (g >= NPN || d >= n) return;
    int beg = rowptr[d], end = rowptr[d + 1];
    auto rowp = [&](int r) {
        return reinterpret_cast<const uint4*>(hs + (size_t)r * S) + fl;
    };
    float s0[8], s1[8] = {0}, s2[8] = {0}, s3[8] = {0};
    h8_set(s0, *rowp(d));  // self
    int p = beg;
    int e0, e1, e2, e3, e4, e5, e6, e7;
    bool have = (p + 8 <= end);
    if (have) {
        e0 = __builtin_nontemporal_load(csr + p);
        e1 = __builtin_nontemporal_load(csr + p + 1);
        e2 = __builtin_nontemporal_load(csr + p + 2);
        e3 = __builtin_nontemporal_load(csr + p + 3);
        e4 = __builtin_nontemporal_load(csr + p + 4);
        e5 = __builtin_nontemporal_load(csr + p + 5);
        e6 = __builtin_nontemporal_load(csr + p + 6);
        e7 = __builtin_nontemporal_load(csr + p + 7);
        p += 8;
    }
    while (have) {
        uint4 v0 = *rowp(e0), v1 = *rowp(e1), v2 = *rowp(e2), v3 = *rowp(e3);
        uint4 v4 = *rowp(e4), v5 = *rowp(e5), v6 = *rowp(e6), v7 = *rowp(e7);
        bool nxt = (p + 8 <= end);
        int f0 = 0, f1 = 0, f2 = 0, f3 = 0, f4 = 0, f5 = 0, f6 = 0, f7 = 0;
        if (nxt) {
            f0 = __builtin_nontemporal_load(csr + p);
            f1 = __builtin_nontemporal_load(csr + p + 1);
            f2 = __builtin_nontemporal_load(csr + p + 2);
            f3 = __builtin_nontemporal_load(csr + p + 3);
            f4 = __builtin_nontemporal_load(csr + p + 4);
            f5 = __builtin_nontemporal_load(csr + p + 5);
            f6 = __builtin_nontemporal_load(csr + p + 6);
            f7 = __builtin_nontemporal_load(csr + p + 7);
            p += 8;
        }
        h8_add(s0, v0); h8_add(s1, v1); h8_add(s2, v2); h8_add(s3, v3);
        h8_add(s0, v4); h8_add(s1, v5); h8_add(s2, v6); h8_add(s3, v7);
        e0 = f0; e1 = f1; e2 = f2; e3 = f3; e4 = f4; e5 = f5; e6 = f6; e7 = f7;
        have = nxt;
    }
    for (; p + 4 <= end; p += 4) {
        int a0 = __builtin_nontemporal_load(csr + p);
        int a1 = __builtin_nontemporal_load(csr + p + 1);
        int a2 = __builtin_nontemporal_load(csr + p + 2);
        int a3 = __builtin_nontemporal_load(csr + p + 3);
        uint4 v0 = *rowp(a0), v1 = *rowp(a1), v2 = *rowp(a2), v3 = *rowp(a3);
        h8_add(s0, v0); h8_add(s1, v1); h8_add(s2, v2); h8_add(s3, v3);
    }
    for (; p < end; ++p) h8_add(s0, *rowp(__builtin_nontemporal_load(csr + p)));
    float dv = dinv[d];
    float r[8];
#pragma unroll
    for (int j = 0; j < 8; ++j) {
        int col = fl * 8 + j;
        float s = (s0[j] + s1[j]) + (s2[j] + s3[j]);
        r[j] = (col < F) ? selu_f(dv * s + bias[col]) : 0.0f;
    }
    float* op = out + (size_t)d * F + fl * 8;
    *reinterpret_cast<float4*>(op) = make_float4(r[0], r[1], r[2], r[3]);
    if (fl * 8 + 4 < F)
        *reinterpret_cast<float4*>(op + 4) = make_float4(r[4], r[5], r[6], r[7]);
}

extern "C" void kernel_launch(void* const* d_in, const int* in_sizes, int n_in,
                              void* d_out, int out_size, void* d_ws, size_t ws_size,
                              hipStream_t stream) {
    const float* x = (const float*)d_in[0];
    const int* ei = (const int*)d_in[1];  // int32 on device
    const float* W1 = (const float*)d_in[2];
    const float* b1 = (const float*)d_in[3];
    const float* W2 = (const float*)d_in[4];
    const float* b2 = (const float*)d_in[5];
    const float* W3 = (const float*)d_in[6];
    const float* b3 = (const float*)d_in[7];
    const float* W4 = (const float*)d_in[8];
    const float* b4 = (const float*)d_in[9];

    int n = in_sizes[0] / 128;
    int e = in_sizes[1] / 2;
    const int* s32 = ei;
    const int* d32 = ei + e;
    int nbkt = (n + CBN - 1) >> CBSH;  // 196

    char* w = (char*)d_ws;
    auto alloc = [&](size_t bytes) {
        char* p = w;
        w += (bytes + 255) & ~(size_t)255;
        return p;
    };
    int* rowptr = (int*)alloc(((size_t)n + 1) * 4);
    float* dinv = (float*)alloc((size_t)n * 4);
    int* csr = (int*)alloc((size_t)e * 4);
    int* H = (int*)alloc((size_t)NB2 * nbkt * 4);
    int* bstart = (int*)alloc(((size_t)nbkt + 1) * 4);
    __half* bufA = (__half*)alloc((size_t)n * 40 * 2);  // hs1/hs3; aliases slab
    __half* bufC = (__half*)alloc((size_t)n * 40 * 2);  // hs2/hs4
    unsigned* slab = (unsigned*)bufA;   // e*4 = 6.4MB <= 8MB

    int nb = (n + BLK - 1) / BLK;

    // CSR build: counting sort + fused build
    k_cnt<<<NB2, BLK, 0, stream>>>(d32, H, e, nbkt);
    k_bsum<<<1, BLK, 0, stream>>>(H, bstart, nbkt, e);
    k_off<<<nbkt, BLK, 0, stream>>>(H, bstart, nbkt);
    k_scatter2<<<NB2, BLK, 0, stream>>>(s32, d32, H, slab, e, nbkt);
    k_build<<<nbkt, BLK, 0, stream>>>(bstart, slab, rowptr, dinv, csr, n, e);

    // grids: nodes/block = 4 waves * NPN (round-18/20 values)
    int ab1 = (n + 127) / 128;  // CHI=2, NPN=32
    int ab2 = (n + 83) / 84;    // CHI=3, NPN=21
    int ab3 = (n + 63) / 64;    // CHI=4, NPN=16
    int ab4 = (n + 47) / 48;    // ACT=5, NPN=12

    // layer 1 gemm: x @ W1 -> hs1 (bufA, stride 16h)
    k_gemm1<<<nb, BLK, 0, stream>>>(x, W1, dinv, bufA, n);

    // fused agg1+gemm2: gather hs1 -> selu epilogue -> @W2 -> hs2 (bufC, stride 32h)
    k_aggemm<2, 32, 16, 15, 20, 3, 32><<<ab1, BLK, 0, stream>>>(
        rowptr, csr, bufA, b1, dinv, W2, bufC, n);

    // fused agg2+gemm3: gather hs2 -> @W3 -> hs3 (bufA, stride 32h)
    k_aggemm<3, 21, 32, 20, 27, 4, 32><<<ab2, BLK, 0, stream>>>(
        rowptr, csr, bufC, b2, dinv, W3, bufA, n);

    // fused agg3+gemm4: gather hs3 -> @W4 -> hs4 (bufC, stride 40h)
    k_aggemm<4, 16, 32, 27, 36, 5, 40><<<ab3, BLK, 0, stream>>>(
        rowptr, csr, bufA, b3, dinv, W4, bufC, n);

    // final agg: gather hs4, fused selu/bias epilogue -> d_out
    k_aggL<36, 40, 5, 12><<<ab4, BLK, 0, stream>>>(rowptr, csr, bufC, (float*)d_out, dinv, b4, n);
}